// Round 3
// baseline (183.667 us; speedup 1.0000x reference)
//
#include <hip/hip_runtime.h>

typedef float f32x4 __attribute__((ext_vector_type(4)));

constexpr int B = 256, N = 512, T = 200, TM1 = 199;
constexpr int JPT = 8;                              // j's per thread
constexpr int SLOTS = 25;                           // ceil(199/8); 25*96B = 2400B = full stats row
constexpr unsigned MAIN_THREADS = (unsigned)B * N * SLOTS;   // 3,276,800
constexpr unsigned MAIN_BLOCKS  = MAIN_THREADS / 256;        // 12,800 exact
constexpr unsigned ITEM_BLOCKS  = ((unsigned)B * TM1) / 256; // 199 exact (256*199 = 50944)
constexpr float MIN_HL = 15.0f / (24.0f * 60.0f);
constexpr float MAX_HL = 274.0f;
constexpr float INV_SPD = 1.0f / 86400.0f;

__device__ __forceinline__ float hl_of(float s0, float s1, float s2,
                                       float th0, float th1, float th2) {
    float logit = fmaf(s0, th0, fmaf(s1, th1, s2 * th2));
    return fminf(fmaxf(exp2f(logit), MIN_HL), MAX_HL);
}

__device__ __forceinline__ float p_of(float hl, float dt_days) {
    float z = exp2f(-dt_days / hl);
    return 1.0f / (1.0f + __expf(-z));   // sigmoid(z), z in (0,1]
}

__global__ __launch_bounds__(256) void hlr_fused(
    const float* __restrict__ x0,
    const float* __restrict__ t,
    const int*   __restrict__ items,
    const float* __restrict__ stats,
    const float* __restrict__ theta,
    float* __restrict__ x_pred,     // (B*N, T)
    float* __restrict__ x_item,     // (B, TM1)
    float* __restrict__ half_life)  // (B*N, TM1)
{
    const float th0 = theta[0], th1 = theta[1], th2 = theta[2];
    const unsigned bid = blockIdx.x;

    if (bid < MAIN_BLOCKS) {
        const unsigned idx  = bid * 256u + threadIdx.x;
        const unsigned row  = idx / SLOTS;           // b*N + n
        const unsigned slot = idx - row * SLOTS;
        const unsigned b    = row >> 9;              // N = 512
        const int j0 = slot * JPT;                   // 0,8,...,192

        // --- stats: 6 aligned 16B loads (row base 2400B, j0*12B with j0%8==0 -> 16B aligned)
        const f32x4* sp = reinterpret_cast<const f32x4*>(
            stats + (size_t)row * (T * 3) + (size_t)j0 * 3);
        float s[24];
        f32x4* sv = reinterpret_cast<f32x4*>(s);
        #pragma unroll
        for (int k = 0; k < 6; ++k) sv[k] = __builtin_nontemporal_load(sp + k);

        // --- t: need t[j0 .. j0+8]; j0%8==0 -> both 16B loads aligned
        const float* trow = t + (size_t)b * T;
        const f32x4 ta = *reinterpret_cast<const f32x4*>(trow + j0);
        const f32x4 tb = *reinterpret_cast<const f32x4*>(trow + j0 + 4);
        const float t8 = (j0 + 8 < T) ? trow[j0 + 8] : 0.f;  // slot 24 doesn't use it
        const float tt[9] = {ta.x, ta.y, ta.z, ta.w, tb.x, tb.y, tb.z, tb.w, t8};

        float hl[JPT], p[JPT];
        #pragma unroll
        for (int i = 0; i < JPT; ++i) {
            hl[i] = hl_of(s[3*i], s[3*i+1], s[3*i+2], th0, th1, th2);
            p[i]  = p_of(hl[i], (tt[i+1] - tt[i]) * INV_SPD);
        }

        float* xp = x_pred    + (size_t)row * T;
        float* hp = half_life + (size_t)row * TM1;

        if (slot == 0) __builtin_nontemporal_store(x0[row], xp);

        if (slot != SLOTS - 1) {
            #pragma unroll
            for (int i = 0; i < JPT; ++i) {
                __builtin_nontemporal_store(p[i],  xp + j0 + 1 + i);
                __builtin_nontemporal_store(hl[i], hp + j0 + i);
            }
        } else {
            #pragma unroll
            for (int i = 0; i < JPT - 1; ++i) {     // j0=192: j 192..198 valid
                __builtin_nontemporal_store(p[i],  xp + j0 + 1 + i);
                __builtin_nontemporal_store(hl[i], hp + j0 + i);
            }
        }
    } else {
        // --- x_item_pred: gather + recompute (tiny: 50,944 threads)
        const int i = (int)(bid - MAIN_BLOCKS) * 256 + (int)threadIdx.x;  // < B*TM1 exactly
        const int b = i / TM1;
        const int j = i - b * TM1;
        const int n = items[(size_t)b * T + j + 1];

        const float* sg = stats + ((size_t)((size_t)b * N + n) * T + j) * 3;
        const float hl = hl_of(sg[0], sg[1], sg[2], th0, th1, th2);
        const float dt = (t[(size_t)b * T + j + 1] - t[(size_t)b * T + j]) * INV_SPD;
        __builtin_nontemporal_store(p_of(hl, dt), x_item + i);
    }
}

extern "C" void kernel_launch(void* const* d_in, const int* in_sizes, int n_in,
                              void* d_out, int out_size, void* d_ws, size_t ws_size,
                              hipStream_t stream) {
    const float* x0    = (const float*)d_in[0];
    const float* t     = (const float*)d_in[1];
    const int*   items = (const int*)d_in[2];
    const float* stats = (const float*)d_in[3];
    const float* theta = (const float*)d_in[4];

    float* out = (float*)d_out;
    float* x_pred    = out;                                        // B*N*T
    float* x_item    = out + (size_t)B * N * T;                    // B*TM1
    float* half_life = out + (size_t)B * N * T + (size_t)B * TM1;  // B*N*TM1

    hlr_fused<<<MAIN_BLOCKS + ITEM_BLOCKS, 256, 0, stream>>>(
        x0, t, items, stats, theta, x_pred, x_item, half_life);
}

// Round 4
// 104.930 us; speedup vs baseline: 1.7504x; 1.7504x over previous
//
#include <hip/hip_runtime.h>

typedef float f32x4 __attribute__((ext_vector_type(4)));

constexpr int B = 256, N = 512, T = 200, TM1 = 199;
constexpr int JPT = 8;                              // j's per thread
constexpr int SLOTS = 25;                           // 25*8 = 200 >= 199; 25*96B = full stats row
constexpr unsigned MAIN_THREADS = (unsigned)B * N * SLOTS;   // 3,276,800
constexpr unsigned MAIN_BLOCKS  = MAIN_THREADS / 256;        // 12,800 exact
constexpr unsigned ITEM_BLOCKS  = ((unsigned)B * TM1) / 256; // 199 exact (256*199 = 50944)
constexpr float MIN_HL = 15.0f / (24.0f * 60.0f);
constexpr float MAX_HL = 274.0f;
constexpr float INV_SPD = 1.0f / 86400.0f;

__device__ __forceinline__ float hl_of(float s0, float s1, float s2,
                                       float th0, float th1, float th2) {
    float logit = fmaf(s0, th0, fmaf(s1, th1, s2 * th2));
    return fminf(fmaxf(exp2f(logit), MIN_HL), MAX_HL);
}

__device__ __forceinline__ float p_of(float hl, float dt_days) {
    float z = exp2f(-dt_days / hl);
    return 1.0f / (1.0f + __expf(-z));   // sigmoid(z), z in (0,1]
}

__global__ __launch_bounds__(256) void hlr_fused(
    const float* __restrict__ x0,
    const float* __restrict__ t,
    const int*   __restrict__ items,
    const float* __restrict__ stats,
    const float* __restrict__ theta,
    float* __restrict__ x_pred,     // (B*N, T)
    float* __restrict__ x_item,     // (B, TM1)
    float* __restrict__ half_life)  // (B*N, TM1)
{
    const float th0 = theta[0], th1 = theta[1], th2 = theta[2];
    const unsigned bid = blockIdx.x;

    if (bid < MAIN_BLOCKS) {
        const unsigned idx  = bid * 256u + threadIdx.x;
        const unsigned row  = idx / SLOTS;           // b*N + n
        const unsigned slot = idx - row * SLOTS;
        const unsigned b    = row >> 9;              // N = 512
        const int j0 = slot * JPT;                   // 0,8,...,192

        // --- stats: 6 aligned 16B loads (row base 2400B, j0*12B with j0%8==0 -> 16B aligned)
        const f32x4* sp = reinterpret_cast<const f32x4*>(
            stats + (size_t)row * (T * 3) + (size_t)j0 * 3);
        float s[24];
        f32x4* sv = reinterpret_cast<f32x4*>(s);
        #pragma unroll
        for (int k = 0; k < 6; ++k) sv[k] = sp[k];

        // --- t: need t[j0 .. j0+8]; j0%8==0 -> both 16B loads aligned
        const float* trow = t + (size_t)b * T;
        const f32x4 ta = *reinterpret_cast<const f32x4*>(trow + j0);
        const f32x4 tb = *reinterpret_cast<const f32x4*>(trow + j0 + 4);
        const float t8 = (j0 + 8 < T) ? trow[j0 + 8] : 0.f;  // slot 24 doesn't use it
        const float tt[9] = {ta.x, ta.y, ta.z, ta.w, tb.x, tb.y, tb.z, tb.w, t8};

        float hl[JPT], p[JPT];
        #pragma unroll
        for (int i = 0; i < JPT; ++i) {
            hl[i] = hl_of(s[3*i], s[3*i+1], s[3*i+2], th0, th1, th2);
            p[i]  = p_of(hl[i], (tt[i+1] - tt[i]) * INV_SPD);
        }

        float* xp = x_pred    + (size_t)row * T;
        float* hp = half_life + (size_t)row * TM1;

        if (slot == 0) xp[0] = x0[row];

        if (slot != SLOTS - 1) {
            #pragma unroll
            for (int i = 0; i < JPT; ++i) {
                xp[j0 + 1 + i] = p[i];
                hp[j0 + i]     = hl[i];
            }
        } else {
            #pragma unroll
            for (int i = 0; i < JPT - 1; ++i) {     // j0=192: j 192..198 valid
                xp[j0 + 1 + i] = p[i];
                hp[j0 + i]     = hl[i];
            }
        }
    } else {
        // --- x_item_pred: gather + recompute (tiny: 50,944 threads)
        const int i = (int)(bid - MAIN_BLOCKS) * 256 + (int)threadIdx.x;  // < B*TM1 exactly
        const int b = i / TM1;
        const int j = i - b * TM1;
        const int n = items[(size_t)b * T + j + 1];

        const float* sg = stats + ((size_t)((size_t)b * N + n) * T + j) * 3;
        const float hl = hl_of(sg[0], sg[1], sg[2], th0, th1, th2);
        const float dt = (t[(size_t)b * T + j + 1] - t[(size_t)b * T + j]) * INV_SPD;
        x_item[i] = p_of(hl, dt);
    }
}

extern "C" void kernel_launch(void* const* d_in, const int* in_sizes, int n_in,
                              void* d_out, int out_size, void* d_ws, size_t ws_size,
                              hipStream_t stream) {
    const float* x0    = (const float*)d_in[0];
    const float* t     = (const float*)d_in[1];
    const int*   items = (const int*)d_in[2];
    const float* stats = (const float*)d_in[3];
    const float* theta = (const float*)d_in[4];

    float* out = (float*)d_out;
    float* x_pred    = out;                                        // B*N*T
    float* x_item    = out + (size_t)B * N * T;                    // B*TM1
    float* half_life = out + (size_t)B * N * T + (size_t)B * TM1;  // B*N*TM1

    hlr_fused<<<MAIN_BLOCKS + ITEM_BLOCKS, 256, 0, stream>>>(
        x0, t, items, stats, theta, x_pred, x_item, half_life);
}